// Round 5
// baseline (1025.191 us; speedup 1.0000x reference)
//
#include <hip/hip_runtime.h>
#include <hip/hip_bf16.h>

typedef _Float16 half8 __attribute__((ext_vector_type(8)));
typedef float f32x4 __attribute__((ext_vector_type(4)));

#define SS 200
#define HH 128
#define NHD 4
#define FH 512
#define NEGF (-4294967295.0f)

// ---------------- pre-kernel: W1 [128][512] f32 -> fp16, MFMA-B-fragment-linear ----------------
// element ((nt*4 + ks)*64 + lane)*8 + j  holds  W1[ks*32 + (lane>>4)*8 + j][nt*16 + (lane&15)]
// Layout confirmed by R3/R4 pass (absmax 1.95e-3).
__global__ void swizzle_w1(const float* __restrict__ W1, _Float16* __restrict__ dst) {
    int tid = blockIdx.x * blockDim.x + threadIdx.x;   // 0..65535
    int j    = tid & 7;
    int lane = (tid >> 3) & 63;
    int ks   = (tid >> 9) & 3;
    int nt   = tid >> 11;
    int k = ks * 32 + (lane >> 4) * 8 + j;
    int n = nt * 16 + (lane & 15);
    dst[tid] = (_Float16)W1[k * FH + n];
}

__device__ __forceinline__ float tanh_fast(float x) {
    x = fminf(fmaxf(x, -15.0f), 15.0f);
    float e = __expf(x + x);
    return (e - 1.0f) * __builtin_amdgcn_rcpf(e + 1.0f);
}

__device__ __forceinline__ f32x4 mfma16(half8 a, half8 b, f32x4 c) {
    return __builtin_amdgcn_mfma_f32_16x16x32_f16(a, b, c, 0, 0, 0);
}

// Block = 1024 threads = 16 waves, one block per batch b.
// Wave w owns n-tiles {2w, 2w+1}; B-fragments resident in VGPRs for the whole kernel.
// NT=1 m-tile in flight -> per-wave VGPR footprint ~110, no spills at cap 128.
template<bool USE_WS>
__global__ __launch_bounds__(1024, 4)
void mhan_main(const float* __restrict__ item, const int* __restrict__ mask,
               const float* __restrict__ pos, const float* __restrict__ W1,
               const float* __restrict__ W2, const _Float16* __restrict__ w1sw,
               float* __restrict__ out)
{
    __shared__ float4 w2s[FH];               // 8 KB
    __shared__ float  attw[208 * NHD];       // 3.3 KB (rows 200..207 pad)
    __shared__ float  part[4][4][HH];        // 8 KB  (head, s-quarter, h)

    int tid  = threadIdx.x;
    int b    = blockIdx.x;
    int lane = tid & 63, wave = tid >> 6;    // wave 0..15
    int q = lane >> 4, c = lane & 15;

    for (int i = tid; i < FH; i += 1024) w2s[i] = ((const float4*)W2)[i];
    for (int i = tid; i < 208 * NHD; i += 1024) attw[i] = 0.0f;
    __syncthreads();

    const float* xb  = item + (size_t)b * SS * HH;
    const half8* w1g = (const half8*)w1sw;

    // ---- resident B-fragments + W2 rows for this wave's two n-tiles ----
    int nta = wave * 2, ntb = nta + 1;
    half8 bf0[4], bf1[4];
#pragma unroll
    for (int ks = 0; ks < 4; ++ks) {
        if (USE_WS) {
            bf0[ks] = w1g[(nta * 4 + ks) * 64 + lane];
            bf1[ks] = w1g[(ntb * 4 + ks) * 64 + lane];
        } else {
#pragma unroll
            for (int j = 0; j < 8; ++j) {
                bf0[ks][j] = (_Float16)W1[(ks * 32 + q * 8 + j) * FH + nta * 16 + c];
                bf1[ks][j] = (_Float16)W1[(ks * 32 + q * 8 + j) * FH + ntb * 16 + c];
            }
        }
    }
    float4 w2a = w2s[nta * 16 + c];
    float4 w2b = w2s[ntb * 16 + c];

    // ---- phase A: per m-tile: A-frags -> 8 MFMA -> tanh -> W2 -> reduce -> LDS atomic ----
    for (int mt = 0; mt < 13; ++mt) {
        int row = mt * 16 + c;
        bool ok = row < SS;
        const float4* xr = (const float4*)(xb + row * HH);
        const float4* pr = (const float4*)(pos + row * HH);
        half8 af[4];
#pragma unroll
        for (int ks = 0; ks < 4; ++ks) {
            int ci = ks * 8 + q * 2;
            float4 x0, x1, p0, p1;
            if (ok) { x0 = xr[ci]; x1 = xr[ci + 1]; p0 = pr[ci]; p1 = pr[ci + 1]; }
            else { x0 = make_float4(0.f,0.f,0.f,0.f); x1 = x0; p0 = x0; p1 = x0; }
            half8 h;
            h[0] = (_Float16)(x0.x + p0.x); h[1] = (_Float16)(x0.y + p0.y);
            h[2] = (_Float16)(x0.z + p0.z); h[3] = (_Float16)(x0.w + p0.w);
            h[4] = (_Float16)(x1.x + p1.x); h[5] = (_Float16)(x1.y + p1.y);
            h[6] = (_Float16)(x1.z + p1.z); h[7] = (_Float16)(x1.w + p1.w);
            af[ks] = h;
        }
        f32x4 acc0 = {0.f,0.f,0.f,0.f}, acc1 = {0.f,0.f,0.f,0.f};
#pragma unroll
        for (int ks = 0; ks < 4; ++ks) {
            acc0 = mfma16(af[ks], bf0[ks], acc0);
            acc1 = mfma16(af[ks], bf1[ks], acc1);
        }
        // C/D map: element r of lane = hidden[mt*16 + q*4 + r][nt*16 + c]
        float attp[4][NHD];
#pragma unroll
        for (int r = 0; r < 4; ++r) {
            float h0 = tanh_fast(acc0[r]);
            float h1 = tanh_fast(acc1[r]);
            attp[r][0] = h0 * w2a.x + h1 * w2b.x;
            attp[r][1] = h0 * w2a.y + h1 * w2b.y;
            attp[r][2] = h0 * w2a.z + h1 * w2b.z;
            attp[r][3] = h0 * w2a.w + h1 * w2b.w;
        }
#pragma unroll
        for (int r = 0; r < 4; ++r)
#pragma unroll
            for (int k = 0; k < NHD; ++k) {
                float v = attp[r][k];
                v += __shfl_xor(v, 1);
                v += __shfl_xor(v, 2);
                v += __shfl_xor(v, 4);
                v += __shfl_xor(v, 8);
                if (c == 0)
                    atomicAdd(&attw[(mt * 16 + q * 4 + r) * NHD + k], v);
            }
    }
    __syncthreads();

    // ---- phase B: masked softmax over S; waves 0..3, head k = wave ----
    if (wave < 4) {
        int k = wave;
        float l[4];
        float m = -__builtin_inff();
#pragma unroll
        for (int i = 0; i < 4; ++i) {
            int s = lane + i * 64;
            if (s < SS) {
                float lv = (mask[(size_t)b * SS + s] != 0) ? attw[s * NHD + k] : NEGF;
                l[i] = lv;
                m = fmaxf(m, lv);
            } else {
                l[i] = -__builtin_inff();
            }
        }
#pragma unroll
        for (int off = 32; off >= 1; off >>= 1) m = fmaxf(m, __shfl_xor(m, off));
        float e[4], sum = 0.0f;
#pragma unroll
        for (int i = 0; i < 4; ++i) {
            e[i] = (l[i] == -__builtin_inff()) ? 0.0f : __expf(l[i] - m);
            sum += e[i];
        }
#pragma unroll
        for (int off = 32; off >= 1; off >>= 1) sum += __shfl_xor(sum, off);
        float inv = __builtin_amdgcn_rcpf(sum);
#pragma unroll
        for (int i = 0; i < 4; ++i) {
            int s = lane + i * 64;
            if (s < SS) attw[s * NHD + k] = e[i] * inv;
        }
    }
    __syncthreads();

    // ---- phase C: interest[k][h] = sum_s w[s,k] x[s,h]; 16 waves = (head, s-quarter) ----
    {
        int k = wave >> 2, jq = wave & 3;
        int s0 = jq * 50;
        float ax = 0.0f, ay = 0.0f;
#pragma unroll 5
        for (int s = s0; s < s0 + 50; ++s) {
            float w = attw[s * NHD + k];
            float2 xv = ((const float2*)(xb + s * HH))[lane];
            ax += w * xv.x;
            ay += w * xv.y;
        }
        part[k][jq][lane * 2]     = ax;
        part[k][jq][lane * 2 + 1] = ay;
    }
    __syncthreads();
    if (tid < 512) {
        int k = tid >> 7, h = tid & 127;
        float v = part[k][0][h] + part[k][1][h] + part[k][2][h] + part[k][3][h];
        out[((size_t)b * NHD + k) * HH + h] = v;
    }
}

extern "C" void kernel_launch(void* const* d_in, const int* in_sizes, int n_in,
                              void* d_out, int out_size, void* d_ws, size_t ws_size,
                              hipStream_t stream) {
    const float* item = (const float*)d_in[0];
    const int*   mask = (const int*)d_in[1];
    const float* pos  = (const float*)d_in[2];
    const float* W1   = (const float*)d_in[3];
    const float* W2   = (const float*)d_in[4];
    float* out = (float*)d_out;

    int B = in_sizes[0] / (SS * HH);
    bool use_ws = ws_size >= (size_t)(HH * FH * sizeof(_Float16));

    if (use_ws) {
        hipLaunchKernelGGL(swizzle_w1, dim3((HH * FH) / 256), dim3(256), 0, stream,
                           W1, (_Float16*)d_ws);
        hipLaunchKernelGGL((mhan_main<true>), dim3(B), dim3(1024), 0, stream,
                           item, mask, pos, W1, W2, (const _Float16*)d_ws, out);
    } else {
        hipLaunchKernelGGL((mhan_main<false>), dim3(B), dim3(1024), 0, stream,
                           item, mask, pos, W1, W2, (const _Float16*)nullptr, out);
    }
}